// Round 4
// baseline (311.282 us; speedup 1.0000x reference)
//
#include <hip/hip_runtime.h>
#include <cfloat>

#define B_   16
#define C_   256
#define K_   1024
#define HW_  4096
#define N_   (B_ * HW_)          // 65536 rows
#define CHW_ (C_ * HW_)          // 1048576

// d_out layout (floats): zq [0, 16777216), seq, losses
#define SEQ_OFF  16777216
#define LOSS_OFF (SEQ_OFF + N_)
// staging inside the zq region (dead after rescue; gather overwrites all):
#define WT_F    0          // w_t f32 [C][K]          (262144 floats)
#define WN_F    262144     // wnorm f32 [K]
#define Q1_F    263168     // q1 f32 [K]  (= 2*c1x*d1w[k])
#define WQ_F    264192     // i8 frag-ordered w hi/lo (524288 bytes = 131072 floats)
#define RLIST_F 395264     // int [131072]
#define RCNT_F  526336     // int

#define EPS_GAP 0.1f
#define XSCL    20.0f      // x fixed scale
#define XINV    0.05f      // dequant step (consistency constant)
#define XOVF    6.3f       // |x| overflow -> forced rescue

typedef int i32x4  __attribute__((ext_vector_type(4)));
typedef int i32x16 __attribute__((ext_vector_type(16)));

__device__ __forceinline__ int pack4b(int b0, int b1, int b2, int b3) {
    return (b0 & 0xFF) | ((b1 & 0xFF) << 8) | ((b2 & 0xFF) << 16) | ((b3 & 0xFF) << 24);
}

// ---------------- prep 1: transpose weight [K][C] -> w_t [C][K] (f32, rescue path) ----------------
__global__ __launch_bounds__(256) void transpose_w_kernel(
    const float* __restrict__ w, float* __restrict__ w_t)
{
    const int tid = blockIdx.x * 256 + threadIdx.x;
    const float4 v = reinterpret_cast<const float4*>(w)[tid];
    const int k = tid >> 6;
    const int c = (tid & 63) * 4;
    w_t[(size_t)(c + 0) * K_ + k] = v.x;
    w_t[(size_t)(c + 1) * K_ + k] = v.y;
    w_t[(size_t)(c + 2) * K_ + k] = v.z;
    w_t[(size_t)(c + 3) * K_ + k] = v.w;
}

// ---------------- prep 2: per-code dynamic-scale i8 hi/lo split, frag-ordered; + wn, q1 ------------
// Layout: chunk32 = 16KB: [tier(hi/lo) 8K [ks 1K [khalf 512 [col*16 [j]]]]]
// B-frag ds_read at (ks): base + ks*1024 + lane*16  (lane: col=l&31, khalf=l>>5)
__global__ __launch_bounds__(256) void wprep_kernel(
    const float* __restrict__ w, unsigned char* __restrict__ wq,
    float* __restrict__ wn, float* __restrict__ q1)
{
    const int t = threadIdx.x;
    const int l = t & 63;
    const int k = blockIdx.x * 4 + (t >> 6);   // one wave per code
    const float4 v4 = *reinterpret_cast<const float4*>(w + (size_t)k * C_ + l * 4);
    float vv[4] = {v4.x, v4.y, v4.z, v4.w};
    float mx = fmaxf(fmaxf(fabsf(vv[0]), fabsf(vv[1])), fmaxf(fabsf(vv[2]), fabsf(vv[3])));
    float s2 = vv[0]*vv[0] + vv[1]*vv[1] + vv[2]*vv[2] + vv[3]*vv[3];
#pragma unroll
    for (int m = 1; m < 64; m <<= 1) {
        mx = fmaxf(mx, __shfl_xor(mx, m, 64));
        s2 += __shfl_xor(s2, m, 64);
    }
    const float s  = 127.4f / fmaxf(mx, 1e-20f);
    const float d1 = 1.0f / s;
    const float sl = s * 256.0f;
    const int chunk = k >> 5;
    const int col   = k & 31;
#pragma unroll
    for (int q = 0; q < 4; ++q) {
        const int c = l * 4 + q;
        const float v = vv[q];
        const int qh = (int)rintf(v * s);                    // |v*s| <= 127.4 -> no clip
        const float r = fmaf((float)qh, -d1, v);
        int ql = (int)rintf(r * sl);
        ql = max(-127, min(127, ql));
        const size_t off = (size_t)chunk * 16384 + (size_t)(c >> 5) * 1024
                         + (size_t)((c >> 4) & 1) * 512 + (size_t)col * 16 + (size_t)(c & 15);
        wq[off]        = (unsigned char)(qh & 0xFF);
        wq[off + 8192] = (unsigned char)(ql & 0xFF);
    }
    if (l == 0) { wn[k] = s2; q1[k] = 0.1f * d1; }           // 2*c1x*d1, c1x=0.05
}

// ---------------- pass A: i8 MFMA approximate argmin with gap flagging ----------------
// 512 blocks x 512 threads (8 waves). Block: 128 rows. Wave wv: m-tile mg=wv&3 (32 rows),
// code-half g2=wv>>2 of each 64-code chunk. A (x) quantized hi/lo in regs (64 VGPR).
// w streamed 32KB/chunk64 via linear global_load_lds (frag-ordered -> conflict-free b128).
__global__ __launch_bounds__(512, 4) void argmin_i8_kernel(
    const float* __restrict__ x, const unsigned char* __restrict__ wq,
    const float* __restrict__ wn, const float* __restrict__ q1,
    float* __restrict__ seq, int* __restrict__ rlist, int* __restrict__ rcount)
{
    __shared__ __align__(16) char lds[65536];   // 2 x 32KB chunk64 buffers; xs aliases buf0
    const int t  = threadIdx.x;
    const int l  = t & 63;
    const int wv = t >> 6;
    const int mg = wv & 3;
    const int g2 = wv >> 2;
    const int col = l & 31;
    const int khalf = l >> 5;
    const int nb = blockIdx.x;
    const int b  = nb >> 5;
    const int hw0 = (nb & 31) << 7;
    const float* xb = x + (size_t)b * CHW_ + hw0;

    char* const buf0 = lds;
    char* const buf1 = lds + 32768;

#define STAGE64(ch, dst)                                                          \
    {                                                                             \
        _Pragma("unroll")                                                         \
        for (int rr = 0; rr < 4; ++rr) {                                          \
            const int sIdx = wv * 4 + rr;                                         \
            __builtin_amdgcn_global_load_lds(                                     \
                (const __attribute__((address_space(1))) void*)                   \
                    (wq + (size_t)(ch) * 32768 + sIdx * 1024 + l * 16),           \
                (__attribute__((address_space(3))) void*)((dst) + sIdx * 1024),   \
                16, 0, 0);                                                        \
        }                                                                         \
    }

    STAGE64(0, buf1);   // prefetch first chunk while x-setup runs (xs uses buf0 only)

    // ---- x staging + two-level i8 quantization into A-fragments ----
    i32x4 ah8[8], al8[8];
    float mx = 0.f;
    {
        float* xs = (float*)buf0;                 // [32 ch][128 rows] f32 = 16KB
#pragma unroll
        for (int cc = 0; cc < 8; ++cc) {
#pragma unroll
            for (int qq = 0; qq < 2; ++qq) {
                const int fi = qq * 512 + t;
                const int cl = fi >> 5;
                const int r4 = (fi & 31) << 2;
                const float4 v = *reinterpret_cast<const float4*>(
                    xb + (size_t)(cc * 32 + cl) * HW_ + r4);
                *reinterpret_cast<float4*>(xs + cl * 128 + r4) = v;
            }
            __syncthreads();
            const int row = mg * 32 + col;
            int qh[16], ql[16];
#pragma unroll
            for (int j = 0; j < 16; ++j) {
                const float v = xs[(khalf * 16 + j) * 128 + row];
                mx = fmaxf(mx, fabsf(v));
                const int h = (int)rintf(v * XSCL);          // overflow rows flagged below
                const float r = fmaf((float)h, -XINV, v);
                int lo = (int)rintf(r * (XSCL * 256.0f));
                lo = max(-127, min(127, lo));
                qh[j] = h; ql[j] = lo;
            }
            ah8[cc] = (i32x4){ pack4b(qh[0],qh[1],qh[2],qh[3]),   pack4b(qh[4],qh[5],qh[6],qh[7]),
                               pack4b(qh[8],qh[9],qh[10],qh[11]), pack4b(qh[12],qh[13],qh[14],qh[15]) };
            al8[cc] = (i32x4){ pack4b(ql[0],ql[1],ql[2],ql[3]),   pack4b(ql[4],ql[5],ql[6],ql[7]),
                               pack4b(ql[8],ql[9],ql[10],ql[11]), pack4b(ql[12],ql[13],ql[14],ql[15]) };
            __syncthreads();
        }
    }

    // overflow rows -> forced exact rescue
    mx = fmaxf(mx, __shfl_xor(mx, 32, 64));
    if (wv < 4 && l < 32 && mx > XOVF) {
        const int pos = atomicAdd(rcount, 1);
        rlist[pos] = b * HW_ + hw0 + mg * 32 + l;
    }

    float m1v[16], m2v[16];
    int   i1v[16];
#pragma unroll
    for (int r = 0; r < 16; ++r) { m1v[r] = FLT_MAX; m2v[r] = FLT_MAX; i1v[r] = 0; }

    for (int ch = 0; ch < 16; ++ch) {
        char* const curbuf = (ch & 1) ? buf0 : buf1;
        if (ch < 15) STAGE64(ch + 1, (ch & 1) ? buf1 : buf0);
        const int kk = ch * 64 + g2 * 32 + col;     // this lane's code
        const float wnv = wn[kk];
        const float q1v = q1[kk];

        i32x16 aH, aX;
#pragma unroll
        for (int r = 0; r < 16; ++r) { aH[r] = 0; aX[r] = 0; }

        const char* base = curbuf + g2 * 16384;
#pragma unroll
        for (int ks = 0; ks < 8; ++ks) {
            const i32x4 bh = *reinterpret_cast<const i32x4*>(base + ks * 1024 + (l << 4));
            const i32x4 bl = *reinterpret_cast<const i32x4*>(base + 8192 + ks * 1024 + (l << 4));
            aH = __builtin_amdgcn_mfma_i32_32x32x32_i8(ah8[ks], bh, aH, 0, 0, 0);
            aX = __builtin_amdgcn_mfma_i32_32x32x32_i8(ah8[ks], bl, aX, 0, 0, 0);
            aX = __builtin_amdgcn_mfma_i32_32x32x32_i8(al8[ks], bh, aX, 0, 0, 0);
        }

        // d = wn - q1*(accHH + accX/256)  (xl*wl dropped; bounded by EPS budget)
#pragma unroll
        for (int r = 0; r < 16; ++r) {
            const float tt = fmaf((float)aX[r], 0.00390625f, (float)aH[r]);
            const float d  = fmaf(-q1v, tt, wnv);
            const bool lt = d < m1v[r];
            m2v[r] = lt ? m1v[r] : fminf(m2v[r], d);
            i1v[r] = lt ? kk : i1v[r];
            m1v[r] = lt ? d : m1v[r];
        }
        __syncthreads();
    }
#undef STAGE64

    // merge across the 32 code-lanes (lane bits 0..4)
#pragma unroll
    for (int mask = 1; mask <= 16; mask <<= 1) {
#pragma unroll
        for (int r = 0; r < 16; ++r) {
            const float om1 = __shfl_xor(m1v[r], mask, 64);
            const int   oi1 = __shfl_xor(i1v[r], mask, 64);
            const float om2 = __shfl_xor(m2v[r], mask, 64);
            const bool lt = om1 < m1v[r] || (om1 == m1v[r] && oi1 < i1v[r]);
            const float nm2 = lt ? fminf(m1v[r], om2) : fminf(m2v[r], om1);
            i1v[r] = lt ? oi1 : i1v[r];
            m1v[r] = lt ? om1 : m1v[r];
            m2v[r] = nm2;
        }
    }

    // cross wave-pair merge (wv and wv+4 share rows, cover disjoint code halves)
    __syncthreads();
    float* fm1 = (float*)lds;          // [128]
    float* fm2 = fm1 + 128;
    int*   fi1 = (int*)(fm2 + 128);
    if (wv >= 4 && col == 0) {
#pragma unroll
        for (int r = 0; r < 16; ++r) {
            const int idx = mg * 32 + khalf * 16 + r;
            fm1[idx] = m1v[r]; fm2[idx] = m2v[r]; fi1[idx] = i1v[r];
        }
    }
    __syncthreads();
    if (wv < 4 && col == 0) {
#pragma unroll
        for (int r = 0; r < 16; ++r) {
            const int idx = mg * 32 + khalf * 16 + r;
            const float om1 = fm1[idx]; const float om2 = fm2[idx]; const int oi1 = fi1[idx];
            const bool lt = om1 < m1v[r] || (om1 == m1v[r] && oi1 < i1v[r]);
            const float nm2 = lt ? fminf(m1v[r], om2) : fminf(m2v[r], om1);
            const int   ni1 = lt ? oi1 : i1v[r];
            const float nm1 = lt ? om1 : m1v[r];
            const int row_local = (r & 3) + 8 * (r >> 2) + 4 * khalf;
            const int n = b * HW_ + hw0 + mg * 32 + row_local;
            seq[n] = (float)ni1;
            if (nm2 - nm1 < EPS_GAP) {
                const int pos = atomicAdd(rcount, 1);
                rlist[pos] = n;
            }
        }
    }
}

// ---------------- rescue: exact f32 re-argmin for flagged rows ----------------
__global__ __launch_bounds__(256) void rescue_kernel(
    const float* __restrict__ x, const float* __restrict__ w_t,
    const float* __restrict__ wnorm, const int* __restrict__ rlist,
    const int* __restrict__ rcount, float* __restrict__ seq)
{
    __shared__ float xr[C_];
    __shared__ float bvs[4];
    __shared__ int   bis[4];
    const int t = threadIdx.x;
    const int cnt = *rcount;
    for (int ii = blockIdx.x; ii < cnt; ii += gridDim.x) {
        const int n = rlist[ii];
        const int b = n >> 12, hw = n & 4095;
        xr[t] = x[(size_t)b * CHW_ + (size_t)t * HW_ + hw];
        __syncthreads();
        float best = FLT_MAX; int bidx = 0;
#pragma unroll
        for (int q = 0; q < 4; ++q) {
            const int k = t + q * 256;
            float acc = 0.f;
            for (int c = 0; c < C_; ++c) acc = fmaf(xr[c], w_t[(size_t)c * K_ + k], acc);
            const float d = wnorm[k] - 2.f * acc;
            if (d < best || (d == best && k < bidx)) { best = d; bidx = k; }
        }
#pragma unroll
        for (int mask = 1; mask < 64; mask <<= 1) {
            const float ov = __shfl_xor(best, mask, 64);
            const int   oi = __shfl_xor(bidx, mask, 64);
            if (ov < best || (ov == best && oi < bidx)) { best = ov; bidx = oi; }
        }
        if ((t & 63) == 0) { bvs[t >> 6] = best; bis[t >> 6] = bidx; }
        __syncthreads();
        if (t == 0) {
            float bv = bvs[0]; int bi = bis[0];
#pragma unroll
            for (int w2 = 1; w2 < 4; ++w2)
                if (bvs[w2] < bv || (bvs[w2] == bv && bis[w2] < bi)) { bv = bvs[w2]; bi = bis[w2]; }
            seq[n] = (float)bi;
        }
        __syncthreads();
    }
}

// ---------------- gather z (via LDS-staged w rows), write zq, accumulate loss ----------------
__global__ __launch_bounds__(256) void gather_kernel(
    const float* __restrict__ x, const float* __restrict__ w,
    const float* __restrict__ seqf, float* __restrict__ zq,
    double* __restrict__ loss_acc)
{
    __shared__ float ws[C_ * 64];      // [c][row] transposed, 64KB exactly
    const int t   = threadIdx.x;
    const int nb  = blockIdx.x;
    const int b   = nb >> 6;
    const int hw0 = (nb & 63) << 6;
    {
        const int j = t >> 2, q = t & 3;
        const int idx = (int)seqf[b * HW_ + hw0 + j];
        const float* wrow = w + (size_t)idx * C_ + q * 64;
#pragma unroll
        for (int m = 0; m < 16; ++m) {
            const float4 v = *reinterpret_cast<const float4*>(wrow + m * 4);
            const int c = q * 64 + m * 4;
            ws[(c + 0) * 64 + j] = v.x;
            ws[(c + 1) * 64 + j] = v.y;
            ws[(c + 2) * 64 + j] = v.z;
            ws[(c + 3) * 64 + j] = v.w;
        }
    }
    __syncthreads();
    const int r  = t & 63;
    const int cg = t >> 6;
    const float* xb = x  + (size_t)b * CHW_ + hw0;
    float*       zb = zq + (size_t)b * CHW_ + hw0;
    float lsum = 0.f;
#pragma unroll 4
    for (int cc = 0; cc < 64; ++cc) {
        const int c = cg * 64 + cc;
        const float xv = xb[(size_t)c * HW_ + r];
        const float d  = ws[c * 64 + r] - xv;
        zb[(size_t)c * HW_ + r] = xv + d;
        lsum += d * d;
    }
#pragma unroll
    for (int off = 32; off >= 1; off >>= 1) lsum += __shfl_down(lsum, off, 64);
    __syncthreads();
    if ((t & 63) == 0) ws[t >> 6] = lsum;
    __syncthreads();
    if (t == 0)
        atomicAdd(loss_acc, (double)(ws[0] + ws[1] + ws[2] + ws[3]));
}

__global__ void finalize_kernel(const double* __restrict__ acc, float* __restrict__ loss_out)
{
    const double s = *acc;
    const float m = (float)(s / (double)((size_t)N_ * C_));
    loss_out[0] = m;
    loss_out[1] = m;
}

extern "C" void kernel_launch(void* const* d_in, const int* in_sizes, int n_in,
                              void* d_out, int out_size, void* d_ws, size_t ws_size,
                              hipStream_t stream)
{
    (void)in_sizes; (void)n_in; (void)out_size; (void)d_ws; (void)ws_size;
    const float* x = (const float*)d_in[0];
    const float* w = (const float*)d_in[1];
    float* out = (float*)d_out;

    float*         w_t    = out + WT_F;
    float*         wn     = out + WN_F;
    float*         q1     = out + Q1_F;
    unsigned char* wq     = (unsigned char*)(out + WQ_F);
    int*           rlist  = (int*)(out + RLIST_F);
    int*           rcount = (int*)(out + RCNT_F);
    float*         seq    = out + SEQ_OFF;
    double*        loss_acc = (double*)(out + LOSS_OFF);

    transpose_w_kernel<<<256, 256, 0, stream>>>(w, w_t);
    wprep_kernel<<<256, 256, 0, stream>>>(w, wq, wn, q1);
    hipMemsetAsync((void*)rcount, 0, 4, stream);
    argmin_i8_kernel<<<512, 512, 0, stream>>>(x, wq, wn, q1, seq, rlist, rcount);
    rescue_kernel<<<1024, 256, 0, stream>>>(x, w_t, wn, rlist, rcount, seq);
    hipMemsetAsync((char*)d_out + (size_t)LOSS_OFF * 4, 0, 8, stream);
    gather_kernel<<<1024, 256, 0, stream>>>(x, w, seq, out, loss_acc);
    finalize_kernel<<<1, 1, 0, stream>>>(loss_acc, out + LOSS_OFF);
}

// Round 6
// 206.513 us; speedup vs baseline: 1.5073x; 1.5073x over previous
//
#include <hip/hip_runtime.h>
#include <cfloat>
#include <climits>

#define B_   16
#define C_   256
#define K_   1024
#define HW_  4096
#define N_   (B_ * HW_)          // 65536 rows
#define CHW_ (C_ * HW_)          // 1048576

// d_out layout (floats): zq [0, 16777216), seq, losses
#define SEQ_OFF  16777216
#define LOSS_OFF (SEQ_OFF + N_)
// staging inside the zq region (dead after rescue; gather overwrites all):
#define WT_F    0          // w_t f32 [C][K]          (262144 floats)
#define WN_F    262144     // wnorm f32 [K]
#define WNU_F   263168     // WNu int [K]  (wn in u-units)
#define WQ_F    264192     // i8 frag-ordered w hi/lo (524288 B = 131072 floats)
#define RLIST_F 395264     // int [131072]
#define RCNT_F  526336     // int
#define WMAX_F  526337     // float (abs-max of w, via atomicMax on bits)

#define RL_CAP  131072
#define EPS_GAP 0.1f       // f32 distance-gap threshold for rescue
#define XSCL    20.0f      // x fixed hi scale
#define XINV    0.05f
#define XOVF    6.3f       // |x| overflow -> forced exact rescue

typedef int i32x4  __attribute__((ext_vector_type(4)));
typedef int i32x16 __attribute__((ext_vector_type(16)));

__device__ __forceinline__ int pack4b(int b0, int b1, int b2, int b3) {
    return (b0 & 0xFF) | ((b1 & 0xFF) << 8) | ((b2 & 0xFF) << 16) | ((b3 & 0xFF) << 24);
}

// ---------------- prep 0: global abs-max of w ----------------
__global__ __launch_bounds__(256) void wmax_kernel(
    const float* __restrict__ w, unsigned* __restrict__ wmax_bits)
{
    const int tid = blockIdx.x * 256 + threadIdx.x;     // 64 blocks -> 16384 threads
    float mx = 0.f;
#pragma unroll
    for (int q = 0; q < 4; ++q) {
        const float4 v = reinterpret_cast<const float4*>(w)[tid * 4 + q];
        mx = fmaxf(mx, fmaxf(fmaxf(fabsf(v.x), fabsf(v.y)), fmaxf(fabsf(v.z), fabsf(v.w))));
    }
#pragma unroll
    for (int m = 1; m < 64; m <<= 1) mx = fmaxf(mx, __shfl_xor(mx, m, 64));
    if ((threadIdx.x & 63) == 0) atomicMax(wmax_bits, __float_as_uint(mx));
}

// ---------------- prep 1: w -> {i8 hi/lo frag-ordered, w_t f32, wn, WNu} ----------------
// Frag layout (proven r4): chunk(k>>5) 16KB block = [hi 8K | lo 8K];
// elem (k, c): off = chunk*16384 + (c>>5)*1024 + ((c>>4)&1)*512 + (k&31)*16 + (c&15)
__global__ __launch_bounds__(256) void wprep_kernel(
    const float* __restrict__ w, const unsigned* __restrict__ wmax_bits,
    unsigned char* __restrict__ wq, float* __restrict__ w_t,
    float* __restrict__ wn, int* __restrict__ wnu)
{
    const int t = threadIdx.x;
    const int l = t & 63;
    const int k = blockIdx.x * 4 + (t >> 6);   // one wave per code
    const float wmx = __uint_as_float(*wmax_bits);
    const float s   = 127.4f / wmx;            // global hi scale
    const float d1  = wmx / 127.4f;
    const float sl  = s * 256.0f;

    const float4 v4 = *reinterpret_cast<const float4*>(w + (size_t)k * C_ + l * 4);
    float vv[4] = {v4.x, v4.y, v4.z, v4.w};
    float s2 = vv[0]*vv[0] + vv[1]*vv[1] + vv[2]*vv[2] + vv[3]*vv[3];
#pragma unroll
    for (int m = 1; m < 64; m <<= 1) s2 += __shfl_xor(s2, m, 64);

    const int chunk = k >> 5;
    const int col   = k & 31;
#pragma unroll
    for (int q = 0; q < 4; ++q) {
        const int c = l * 4 + q;
        const float v = vv[q];
        const int qh = (int)rintf(v * s);                     // |.| <= 127
        const float r = fmaf((float)qh, -d1, v);
        int ql = (int)rintf(r * sl);
        ql = max(-127, min(127, ql));
        const size_t off = (size_t)chunk * 16384 + (size_t)(c >> 5) * 1024
                         + (size_t)((c >> 4) & 1) * 512 + (size_t)col * 16 + (size_t)(c & 15);
        wq[off]        = (unsigned char)(qh & 0xFF);
        wq[off + 8192] = (unsigned char)(ql & 0xFF);
        w_t[(size_t)c * K_ + k] = v;                          // f32 transpose for rescue
    }
    if (l == 0) {
        wn[k] = s2;
        wnu[k] = (int)rintf(s2 * (2560.0f / d1));             // wn / u, u = d1/2560
    }
}

// ---------------- pass A: i8 two-level MFMA argmin, packed-int min1/min2 ----------------
// 512 blocks x 256 threads (4 waves). Block: 128 rows. Wave wv: rows wv*32..+31.
// x hi/lo A-frags in regs (64 VGPR). w streamed 16KB/chunk32 via linear
// global_load_lds (frag-ordered -> conflict-free lane-contiguous ds_read_b128).
// Distances in integer u-units; min1 packed with 5-bit chunk id in low bits.
__global__ __launch_bounds__(256) void argmin_i8_kernel(
    const float* __restrict__ x, const unsigned char* __restrict__ wq,
    const int* __restrict__ wnu, const unsigned* __restrict__ wmax_bits,
    float* __restrict__ seq, int* __restrict__ rlist, int* __restrict__ rcount)
{
    __shared__ __align__(16) char lds[32768];   // 2 x 16KB chunk buffers; xs aliases buf0
    const int t  = threadIdx.x;
    const int l  = t & 63;
    const int wv = t >> 6;
    const int col = l & 31;
    const int khalf = l >> 5;
    const int nb = blockIdx.x;
    const int b  = nb >> 5;
    const int hw0 = (nb & 31) << 7;
    const float* xb = x + (size_t)b * CHW_ + hw0;

    char* const buf0 = lds;
    char* const buf1 = lds + 16384;

#define STAGE32(ch, dst)                                                          \
    {                                                                             \
        _Pragma("unroll")                                                         \
        for (int rr = 0; rr < 4; ++rr) {                                          \
            const int sIdx = wv * 4 + rr;                                         \
            __builtin_amdgcn_global_load_lds(                                     \
                (const __attribute__((address_space(1))) void*)                   \
                    (wq + (size_t)(ch) * 16384 + sIdx * 1024 + l * 16),           \
                (__attribute__((address_space(3))) void*)((dst) + sIdx * 1024),   \
                16, 0, 0);                                                        \
        }                                                                         \
    }

    STAGE32(0, buf1);   // prefetch chunk 0 while x-setup runs in buf0

    // ---- x staging + two-level i8 quantization into A-fragments ----
    i32x4 ah8[8], al8[8];
    float mx = 0.f;
    {
        float* xs = (float*)buf0;                 // [32 ch][128 rows] f32 = 16KB
        const int row = wv * 32 + col;
#pragma unroll
        for (int cc = 0; cc < 8; ++cc) {
#pragma unroll
            for (int qq = 0; qq < 4; ++qq) {      // FIX r5: 4 iters cover all 1024 float4 slots
                const int fi = qq * 256 + t;
                const int cl = fi >> 5;           // 0..31
                const int r4 = (fi & 31) << 2;    // 0..124
                const float4 v = *reinterpret_cast<const float4*>(
                    xb + (size_t)(cc * 32 + cl) * HW_ + r4);
                *reinterpret_cast<float4*>(xs + cl * 128 + r4) = v;
            }
            __syncthreads();
            int qh[16], ql[16];
#pragma unroll
            for (int j = 0; j < 16; ++j) {
                const float v = xs[(khalf * 16 + j) * 128 + row];
                mx = fmaxf(mx, fabsf(v));
                int h = (int)rintf(v * XSCL);
                h = max(-127, min(127, h));
                const float r = fmaf((float)h, -XINV, v);
                int lo = (int)rintf(r * (XSCL * 256.0f));
                lo = max(-127, min(127, lo));
                qh[j] = h; ql[j] = lo;
            }
            ah8[cc] = (i32x4){ pack4b(qh[0],qh[1],qh[2],qh[3]),   pack4b(qh[4],qh[5],qh[6],qh[7]),
                               pack4b(qh[8],qh[9],qh[10],qh[11]), pack4b(qh[12],qh[13],qh[14],qh[15]) };
            al8[cc] = (i32x4){ pack4b(ql[0],ql[1],ql[2],ql[3]),   pack4b(ql[4],ql[5],ql[6],ql[7]),
                               pack4b(ql[8],ql[9],ql[10],ql[11]), pack4b(ql[12],ql[13],ql[14],ql[15]) };
            __syncthreads();
        }
    }

    // overflow rows -> forced exact rescue (lane covers half the channels of its row)
    mx = fmaxf(mx, __shfl_xor(mx, 32, 64));
    if (khalf == 0 && mx > XOVF) {
        const int pos = atomicAdd(rcount, 1);
        if (pos < RL_CAP) rlist[pos] = b * HW_ + hw0 + wv * 32 + col;
    }

    const float wmx = __uint_as_float(*wmax_bits);
    const int eps_u = (int)(32614.4f / wmx);   // EPS_GAP * 2560 * 127.4 / wmax

    int m1p[16], m2p[16];
#pragma unroll
    for (int r = 0; r < 16; ++r) { m1p[r] = INT_MAX; m2p[r] = INT_MAX; }

    for (int ch = 0; ch < 32; ++ch) {
        char* const curbuf = (ch & 1) ? buf0 : buf1;
        if (ch < 31) STAGE32(ch + 1, (ch & 1) ? buf1 : buf0);
        const int wnu_l = wnu[ch * 32 + col];

        i32x16 aH, aX;
#pragma unroll
        for (int r = 0; r < 16; ++r) { aH[r] = 0; aX[r] = 0; }

#pragma unroll
        for (int ks = 0; ks < 8; ++ks) {
            const i32x4 bh = *reinterpret_cast<const i32x4*>(curbuf + ks * 1024 + (l << 4));
            const i32x4 bl = *reinterpret_cast<const i32x4*>(curbuf + 8192 + ks * 1024 + (l << 4));
            aH = __builtin_amdgcn_mfma_i32_32x32x32_i8(ah8[ks], bh, aH, 0, 0, 0);
            aX = __builtin_amdgcn_mfma_i32_32x32x32_i8(ah8[ks], bl, aX, 0, 0, 0);
            aX = __builtin_amdgcn_mfma_i32_32x32x32_i8(al8[ks], bh, aX, 0, 0, 0);
        }

        // D = WNu - (aH*256 + aX); pack chunk id in 5 LSBs; min1/min2 update
#pragma unroll
        for (int r = 0; r < 16; ++r) {
            const int T  = (aH[r] << 8) + aX[r];
            const int D  = wnu_l - T;
            const int Dp = (D & ~31) | ch;
            m2p[r] = min(m2p[r], max(m1p[r], Dp));
            m1p[r] = min(m1p[r], Dp);
        }
        __syncthreads();
    }
#undef STAGE32

    // rebuild k, then merge across the 32 code-lanes (lane bits 0..4)
    int k1[16];
#pragma unroll
    for (int r = 0; r < 16; ++r) k1[r] = ((m1p[r] & 31) << 5) | col;
#pragma unroll
    for (int mask = 1; mask <= 16; mask <<= 1) {
#pragma unroll
        for (int r = 0; r < 16; ++r) {
            const int om1 = __shfl_xor(m1p[r], mask, 64);
            const int ok1 = __shfl_xor(k1[r],  mask, 64);
            const int om2 = __shfl_xor(m2p[r], mask, 64);
            const int nm2 = min(min(m2p[r], om2), max(m1p[r], om1));
            const bool lt = om1 < m1p[r] || (om1 == m1p[r] && ok1 < k1[r]);
            m1p[r] = lt ? om1 : m1p[r];
            k1[r]  = lt ? ok1 : k1[r];
            m2p[r] = nm2;
        }
    }

    if (col == 0) {
#pragma unroll
        for (int r = 0; r < 16; ++r) {
            const int row_local = (r & 3) + 8 * (r >> 2) + 4 * khalf;   // 0..31
            const int n = b * HW_ + hw0 + wv * 32 + row_local;
            seq[n] = (float)k1[r];
            if (m2p[r] - m1p[r] < eps_u) {
                const int pos = atomicAdd(rcount, 1);
                if (pos < RL_CAP) rlist[pos] = n;
            }
        }
    }
}

// ---------------- rescue: exact f32 re-argmin for flagged rows ----------------
__global__ __launch_bounds__(256) void rescue_kernel(
    const float* __restrict__ x, const float* __restrict__ w_t,
    const float* __restrict__ wnorm, const int* __restrict__ rlist,
    const int* __restrict__ rcount, float* __restrict__ seq)
{
    __shared__ float xr[C_];
    __shared__ float bvs[4];
    __shared__ int   bis[4];
    const int t = threadIdx.x;
    const int cnt = min(*rcount, RL_CAP);
    for (int ii = blockIdx.x; ii < cnt; ii += gridDim.x) {
        const int n = rlist[ii];
        const int b = n >> 12, hw = n & 4095;
        xr[t] = x[(size_t)b * CHW_ + (size_t)t * HW_ + hw];
        __syncthreads();
        float best = FLT_MAX; int bidx = 0;
#pragma unroll
        for (int q = 0; q < 4; ++q) {
            const int k = t + q * 256;
            float acc = 0.f;
            for (int c = 0; c < C_; ++c) acc = fmaf(xr[c], w_t[(size_t)c * K_ + k], acc);
            const float d = wnorm[k] - 2.f * acc;
            if (d < best || (d == best && k < bidx)) { best = d; bidx = k; }
        }
#pragma unroll
        for (int mask = 1; mask < 64; mask <<= 1) {
            const float ov = __shfl_xor(best, mask, 64);
            const int   oi = __shfl_xor(bidx, mask, 64);
            if (ov < best || (ov == best && oi < bidx)) { best = ov; bidx = oi; }
        }
        if ((t & 63) == 0) { bvs[t >> 6] = best; bis[t >> 6] = bidx; }
        __syncthreads();
        if (t == 0) {
            float bv = bvs[0]; int bi = bis[0];
#pragma unroll
            for (int w2 = 1; w2 < 4; ++w2)
                if (bvs[w2] < bv || (bvs[w2] == bv && bis[w2] < bi)) { bv = bvs[w2]; bi = bis[w2]; }
            seq[n] = (float)bi;
        }
        __syncthreads();
    }
}

// ---------------- gather z (via LDS-staged w rows), write zq, accumulate loss ----------------
__global__ __launch_bounds__(256) void gather_kernel(
    const float* __restrict__ x, const float* __restrict__ w,
    const float* __restrict__ seqf, float* __restrict__ zq,
    double* __restrict__ loss_acc)
{
    __shared__ float ws[C_ * 64];      // [c][row] transposed, 64KB
    const int t   = threadIdx.x;
    const int nb  = blockIdx.x;
    const int b   = nb >> 6;
    const int hw0 = (nb & 63) << 6;
    {
        const int j = t >> 2, q = t & 3;
        const int idx = (int)seqf[b * HW_ + hw0 + j];
        const float* wrow = w + (size_t)idx * C_ + q * 64;
#pragma unroll
        for (int m = 0; m < 16; ++m) {
            const float4 v = *reinterpret_cast<const float4*>(wrow + m * 4);
            const int c = q * 64 + m * 4;
            ws[(c + 0) * 64 + j] = v.x;
            ws[(c + 1) * 64 + j] = v.y;
            ws[(c + 2) * 64 + j] = v.z;
            ws[(c + 3) * 64 + j] = v.w;
        }
    }
    __syncthreads();
    const int r  = t & 63;
    const int cg = t >> 6;
    const float* xb = x  + (size_t)b * CHW_ + hw0;
    float*       zb = zq + (size_t)b * CHW_ + hw0;
    float lsum = 0.f;
#pragma unroll 4
    for (int cc = 0; cc < 64; ++cc) {
        const int c = cg * 64 + cc;
        const float xv = xb[(size_t)c * HW_ + r];
        const float d  = ws[c * 64 + r] - xv;
        zb[(size_t)c * HW_ + r] = xv + d;
        lsum += d * d;
    }
#pragma unroll
    for (int off = 32; off >= 1; off >>= 1) lsum += __shfl_down(lsum, off, 64);
    __syncthreads();
    if ((t & 63) == 0) ws[t >> 6] = lsum;
    __syncthreads();
    if (t == 0)
        atomicAdd(loss_acc, (double)(ws[0] + ws[1] + ws[2] + ws[3]));
}

__global__ void finalize_kernel(const double* __restrict__ acc, float* __restrict__ loss_out)
{
    const double s = *acc;
    const float m = (float)(s / (double)((size_t)N_ * C_));
    loss_out[0] = m;
    loss_out[1] = m;
}

extern "C" void kernel_launch(void* const* d_in, const int* in_sizes, int n_in,
                              void* d_out, int out_size, void* d_ws, size_t ws_size,
                              hipStream_t stream)
{
    (void)in_sizes; (void)n_in; (void)out_size; (void)d_ws; (void)ws_size;
    const float* x = (const float*)d_in[0];
    const float* w = (const float*)d_in[1];
    float* out = (float*)d_out;

    float*         w_t    = out + WT_F;
    float*         wn     = out + WN_F;
    int*           wnu    = (int*)(out + WNU_F);
    unsigned char* wq     = (unsigned char*)(out + WQ_F);
    int*           rlist  = (int*)(out + RLIST_F);
    int*           rcount = (int*)(out + RCNT_F);
    unsigned*      wmaxb  = (unsigned*)(out + WMAX_F);
    float*         seq    = out + SEQ_OFF;
    double*        loss_acc = (double*)(out + LOSS_OFF);

    hipMemsetAsync((void*)wmaxb, 0, 4, stream);
    hipMemsetAsync((void*)rcount, 0, 4, stream);
    wmax_kernel<<<64, 256, 0, stream>>>(w, wmaxb);
    wprep_kernel<<<256, 256, 0, stream>>>(w, wmaxb, wq, w_t, wn, wnu);
    argmin_i8_kernel<<<512, 256, 0, stream>>>(x, wq, wnu, wmaxb, seq, rlist, rcount);
    rescue_kernel<<<1024, 256, 0, stream>>>(x, w_t, wn, rlist, rcount, seq);
    hipMemsetAsync((char*)d_out + (size_t)LOSS_OFF * 4, 0, 8, stream);
    gather_kernel<<<1024, 256, 0, stream>>>(x, w, seq, out, loss_acc);
    finalize_kernel<<<1, 1, 0, stream>>>(loss_acc, out + LOSS_OFF);
}

// Round 7
// 190.394 us; speedup vs baseline: 1.6349x; 1.0847x over previous
//
#include <hip/hip_runtime.h>
#include <cfloat>
#include <climits>

#define B_   16
#define C_   256
#define K_   1024
#define HW_  4096
#define N_   (B_ * HW_)          // 65536 rows
#define CHW_ (C_ * HW_)          // 1048576

// d_out layout (floats): zq [0, 16777216), seq, losses
#define SEQ_OFF  16777216
#define LOSS_OFF (SEQ_OFF + N_)
// staging inside the zq region (dead after rescue; gather overwrites all):
#define WT_F    0          // w_t f32 [C][K]          (262144 floats)
#define WN_F    262144     // wnorm f32 [K]
#define WNU_F   263168     // WNu int [K]  (wn in u-units)
#define WQ_F    264192     // i8 frag-ordered w hi/lo (524288 B = 131072 floats)
#define RLIST_F 395264     // int [131072]
#define RCNT_F  526336     // int
#define WMAX_F  526337     // float (abs-max of w, via atomicMax on bits)

#define RL_CAP  131072
#define EPS_GAP 0.1f       // f32 distance-gap threshold for rescue
#define XSCL    20.0f      // x fixed hi scale
#define XINV    0.05f
#define XOVF    6.3f       // |x| overflow -> forced exact rescue

typedef int i32x4  __attribute__((ext_vector_type(4)));
typedef int i32x16 __attribute__((ext_vector_type(16)));

__device__ __forceinline__ int pack4b(int b0, int b1, int b2, int b3) {
    return (b0 & 0xFF) | ((b1 & 0xFF) << 8) | ((b2 & 0xFF) << 16) | ((b3 & 0xFF) << 24);
}

// ---------------- prep 0: global abs-max of w ----------------
__global__ __launch_bounds__(256) void wmax_kernel(
    const float* __restrict__ w, unsigned* __restrict__ wmax_bits)
{
    const int tid = blockIdx.x * 256 + threadIdx.x;     // 64 blocks -> 16384 threads
    float mx = 0.f;
#pragma unroll
    for (int q = 0; q < 4; ++q) {
        const float4 v = reinterpret_cast<const float4*>(w)[tid * 4 + q];
        mx = fmaxf(mx, fmaxf(fmaxf(fabsf(v.x), fabsf(v.y)), fmaxf(fabsf(v.z), fabsf(v.w))));
    }
#pragma unroll
    for (int m = 1; m < 64; m <<= 1) mx = fmaxf(mx, __shfl_xor(mx, m, 64));
    if ((threadIdx.x & 63) == 0) atomicMax(wmax_bits, __float_as_uint(mx));
}

// ---------------- prep 1: w -> {i8 hi/lo frag-ordered, w_t f32, wn, WNu} ----------------
// Frag layout (proven r4/r6): chunk(k>>5) 16KB block = [hi 8K | lo 8K];
// elem (k, c): off = chunk*16384 + (c>>5)*1024 + ((c>>4)&1)*512 + (k&31)*16 + (c&15)
__global__ __launch_bounds__(256) void wprep_kernel(
    const float* __restrict__ w, const unsigned* __restrict__ wmax_bits,
    unsigned char* __restrict__ wq, float* __restrict__ w_t,
    float* __restrict__ wn, int* __restrict__ wnu)
{
    const int t = threadIdx.x;
    const int l = t & 63;
    const int k = blockIdx.x * 4 + (t >> 6);   // one wave per code
    const float wmx = __uint_as_float(*wmax_bits);
    const float s   = 127.4f / wmx;            // global hi scale
    const float d1  = wmx / 127.4f;
    const float sl  = s * 256.0f;

    const float4 v4 = *reinterpret_cast<const float4*>(w + (size_t)k * C_ + l * 4);
    float vv[4] = {v4.x, v4.y, v4.z, v4.w};
    float s2 = vv[0]*vv[0] + vv[1]*vv[1] + vv[2]*vv[2] + vv[3]*vv[3];
#pragma unroll
    for (int m = 1; m < 64; m <<= 1) s2 += __shfl_xor(s2, m, 64);

    const int chunk = k >> 5;
    const int col   = k & 31;
#pragma unroll
    for (int q = 0; q < 4; ++q) {
        const int c = l * 4 + q;
        const float v = vv[q];
        const int qh = (int)rintf(v * s);                     // |.| <= 127
        const float r = fmaf((float)qh, -d1, v);
        int ql = (int)rintf(r * sl);
        ql = max(-127, min(127, ql));
        const size_t off = (size_t)chunk * 16384 + (size_t)(c >> 5) * 1024
                         + (size_t)((c >> 4) & 1) * 512 + (size_t)col * 16 + (size_t)(c & 15);
        wq[off]        = (unsigned char)(qh & 0xFF);
        wq[off + 8192] = (unsigned char)(ql & 0xFF);
        w_t[(size_t)c * K_ + k] = v;                          // f32 transpose for rescue
    }
    if (l == 0) {
        wn[k] = s2;
        wnu[k] = (int)rintf(s2 * (2560.0f / d1));             // wn / u, u = d1/2560
    }
}

// ---------------- pass A: i8 two-level MFMA argmin, T3+T4 deep pipeline ----------------
// 512 blocks x 256 threads (4 waves). Block: 128 rows. Wave wv: rows wv*32..+31.
// 4 LDS chunk buffers, 3 chunks in flight, counted vmcnt (never 0 in main loop),
// raw s_barrier (no compiler vmcnt(0) drain). Math identical to r6 (validated).
__global__ __launch_bounds__(256) void argmin_i8_kernel(
    const float* __restrict__ x, const unsigned char* __restrict__ wq,
    const int* __restrict__ wnu, const unsigned* __restrict__ wmax_bits,
    float* __restrict__ seq, int* __restrict__ rlist, int* __restrict__ rcount)
{
    __shared__ __align__(16) char lds[69632];   // 4 x 16KB chunk bufs + 4KB wnu; xs aliases buf0
    const int t  = threadIdx.x;
    const int l  = t & 63;
    const int wv = t >> 6;
    const int col = l & 31;
    const int khalf = l >> 5;
    const int nb = blockIdx.x;
    const int b  = nb >> 5;
    const int hw0 = (nb & 31) << 7;
    const float* xb = x + (size_t)b * CHW_ + hw0;
    int* const wnu_lds = (int*)(lds + 65536);

#define STAGE32(ch, dst)                                                          \
    {                                                                             \
        _Pragma("unroll")                                                         \
        for (int rr = 0; rr < 4; ++rr) {                                          \
            const int sIdx = wv * 4 + rr;                                         \
            __builtin_amdgcn_global_load_lds(                                     \
                (const __attribute__((address_space(1))) void*)                   \
                    (wq + (size_t)(ch) * 16384 + sIdx * 1024 + l * 16),           \
                (__attribute__((address_space(3))) void*)((dst) + sIdx * 1024),   \
                16, 0, 0);                                                        \
        }                                                                         \
    }

    // wnu -> LDS (visible to all after x-setup's first __syncthreads)
#pragma unroll
    for (int i = 0; i < 4; ++i) wnu_lds[t + i * 256] = wnu[t + i * 256];

    // ---- x staging + two-level i8 quantization into A-fragments (r6-validated) ----
    i32x4 ah8[8], al8[8];
    float mx = 0.f;
    {
        float* xs = (float*)lds;                  // [32 ch][128 rows] f32 = 16KB (buf0)
        const int row = wv * 32 + col;
#pragma unroll
        for (int cc = 0; cc < 8; ++cc) {
#pragma unroll
            for (int qq = 0; qq < 4; ++qq) {      // 4 iters cover all 1024 float4 slots
                const int fi = qq * 256 + t;
                const int cl = fi >> 5;           // 0..31
                const int r4 = (fi & 31) << 2;    // 0..124
                const float4 v = *reinterpret_cast<const float4*>(
                    xb + (size_t)(cc * 32 + cl) * HW_ + r4);
                *reinterpret_cast<float4*>(xs + cl * 128 + r4) = v;
            }
            __syncthreads();
            int qh[16], ql[16];
#pragma unroll
            for (int j = 0; j < 16; ++j) {
                const float v = xs[(khalf * 16 + j) * 128 + row];
                mx = fmaxf(mx, fabsf(v));
                int h = (int)rintf(v * XSCL);
                h = max(-127, min(127, h));
                const float r = fmaf((float)h, -XINV, v);
                int lo = (int)rintf(r * (XSCL * 256.0f));
                lo = max(-127, min(127, lo));
                qh[j] = h; ql[j] = lo;
            }
            ah8[cc] = (i32x4){ pack4b(qh[0],qh[1],qh[2],qh[3]),   pack4b(qh[4],qh[5],qh[6],qh[7]),
                               pack4b(qh[8],qh[9],qh[10],qh[11]), pack4b(qh[12],qh[13],qh[14],qh[15]) };
            al8[cc] = (i32x4){ pack4b(ql[0],ql[1],ql[2],ql[3]),   pack4b(ql[4],ql[5],ql[6],ql[7]),
                               pack4b(ql[8],ql[9],ql[10],ql[11]), pack4b(ql[12],ql[13],ql[14],ql[15]) };
            __syncthreads();
        }
    }

    // overflow rows -> forced exact rescue
    mx = fmaxf(mx, __shfl_xor(mx, 32, 64));
    if (khalf == 0 && mx > XOVF) {
        const int pos = atomicAdd(rcount, 1);
        if (pos < RL_CAP) rlist[pos] = b * HW_ + hw0 + wv * 32 + col;
    }

    const float wmx = __uint_as_float(*wmax_bits);
    const int eps_u = (int)(32614.4f / wmx);   // EPS_GAP * 2560 * 127.4 / wmax

    int m1p[16], m2p[16];
#pragma unroll
    for (int r = 0; r < 16; ++r) { m1p[r] = INT_MAX; m2p[r] = INT_MAX; }

    // ---- pipeline prologue: 3 chunks in flight (12 loads/wave) ----
    STAGE32(0, lds);
    STAGE32(1, lds + 16384);
    STAGE32(2, lds + 32768);

    // waits: retire oldest chunk (mine), then barrier (everyone's), no drain
#define WAITS(VM)                                                     \
    asm volatile("s_waitcnt lgkmcnt(0)" ::: "memory");                \
    __builtin_amdgcn_sched_barrier(0);                                \
    asm volatile("s_waitcnt vmcnt(" VM ")" ::: "memory");             \
    __builtin_amdgcn_s_barrier();                                     \
    __builtin_amdgcn_sched_barrier(0);

#define CHUNK_COMPUTE(ch)                                                         \
    {                                                                             \
        const char* curbuf = lds + ((ch) & 3) * 16384;                            \
        const int wnu_l = wnu_lds[(ch) * 32 + col];                               \
        i32x16 aH, aX;                                                            \
        _Pragma("unroll")                                                         \
        for (int r = 0; r < 16; ++r) { aH[r] = 0; aX[r] = 0; }                    \
        __builtin_amdgcn_s_setprio(1);                                            \
        _Pragma("unroll")                                                         \
        for (int ks = 0; ks < 8; ++ks) {                                          \
            const i32x4 bh = *reinterpret_cast<const i32x4*>(                     \
                curbuf + ks * 1024 + (l << 4));                                   \
            const i32x4 bl = *reinterpret_cast<const i32x4*>(                     \
                curbuf + 8192 + ks * 1024 + (l << 4));                            \
            aH = __builtin_amdgcn_mfma_i32_32x32x32_i8(ah8[ks], bh, aH, 0, 0, 0); \
            aX = __builtin_amdgcn_mfma_i32_32x32x32_i8(ah8[ks], bl, aX, 0, 0, 0); \
            aX = __builtin_amdgcn_mfma_i32_32x32x32_i8(al8[ks], bh, aX, 0, 0, 0); \
        }                                                                         \
        __builtin_amdgcn_s_setprio(0);                                            \
        _Pragma("unroll")                                                         \
        for (int r = 0; r < 16; ++r) {                                            \
            const int T  = (aH[r] << 8) + aX[r];                                  \
            const int D  = wnu_l - T;                                             \
            const int Dp = (D & ~31) | (ch);                                      \
            m2p[r] = min(m2p[r], max(m1p[r], Dp));                                \
            m1p[r] = min(m1p[r], Dp);                                             \
        }                                                                         \
    }

#pragma unroll 1
    for (int ch = 0; ch < 30; ++ch) {
        WAITS("8");                                  // oldest (ch) of 3 in-flight retired
        if (ch <= 28) STAGE32(ch + 3, lds + ((ch + 3) & 3) * 16384);
        CHUNK_COMPUTE(ch);
    }
    WAITS("4");
    CHUNK_COMPUTE(30);
    WAITS("0");
    CHUNK_COMPUTE(31);
#undef WAITS
#undef STAGE32

    // rebuild k, then merge across the 32 code-lanes (lane bits 0..4)
    int k1[16];
#pragma unroll
    for (int r = 0; r < 16; ++r) k1[r] = ((m1p[r] & 31) << 5) | col;
#pragma unroll
    for (int mask = 1; mask <= 16; mask <<= 1) {
#pragma unroll
        for (int r = 0; r < 16; ++r) {
            const int om1 = __shfl_xor(m1p[r], mask, 64);
            const int ok1 = __shfl_xor(k1[r],  mask, 64);
            const int om2 = __shfl_xor(m2p[r], mask, 64);
            const int nm2 = min(min(m2p[r], om2), max(m1p[r], om1));
            const bool lt = om1 < m1p[r] || (om1 == m1p[r] && ok1 < k1[r]);
            m1p[r] = lt ? om1 : m1p[r];
            k1[r]  = lt ? ok1 : k1[r];
            m2p[r] = nm2;
        }
    }

    if (col == 0) {
#pragma unroll
        for (int r = 0; r < 16; ++r) {
            const int row_local = (r & 3) + 8 * (r >> 2) + 4 * khalf;   // 0..31
            const int n = b * HW_ + hw0 + wv * 32 + row_local;
            seq[n] = (float)k1[r];
            if (m2p[r] - m1p[r] < eps_u) {
                const int pos = atomicAdd(rcount, 1);
                if (pos < RL_CAP) rlist[pos] = n;
            }
        }
    }
}

// ---------------- rescue: exact f32 re-argmin for flagged rows ----------------
__global__ __launch_bounds__(256) void rescue_kernel(
    const float* __restrict__ x, const float* __restrict__ w_t,
    const float* __restrict__ wnorm, const int* __restrict__ rlist,
    const int* __restrict__ rcount, float* __restrict__ seq)
{
    __shared__ float xr[C_];
    __shared__ float bvs[4];
    __shared__ int   bis[4];
    const int t = threadIdx.x;
    const int cnt = min(*rcount, RL_CAP);
    for (int ii = blockIdx.x; ii < cnt; ii += gridDim.x) {
        const int n = rlist[ii];
        const int b = n >> 12, hw = n & 4095;
        xr[t] = x[(size_t)b * CHW_ + (size_t)t * HW_ + hw];
        __syncthreads();
        float best = FLT_MAX; int bidx = 0;
#pragma unroll
        for (int q = 0; q < 4; ++q) {
            const int k = t + q * 256;
            float acc = 0.f;
            for (int c = 0; c < C_; ++c) acc = fmaf(xr[c], w_t[(size_t)c * K_ + k], acc);
            const float d = wnorm[k] - 2.f * acc;
            if (d < best || (d == best && k < bidx)) { best = d; bidx = k; }
        }
#pragma unroll
        for (int mask = 1; mask < 64; mask <<= 1) {
            const float ov = __shfl_xor(best, mask, 64);
            const int   oi = __shfl_xor(bidx, mask, 64);
            if (ov < best || (ov == best && oi < bidx)) { best = ov; bidx = oi; }
        }
        if ((t & 63) == 0) { bvs[t >> 6] = best; bis[t >> 6] = bidx; }
        __syncthreads();
        if (t == 0) {
            float bv = bvs[0]; int bi = bis[0];
#pragma unroll
            for (int w2 = 1; w2 < 4; ++w2)
                if (bvs[w2] < bv || (bvs[w2] == bv && bis[w2] < bi)) { bv = bvs[w2]; bi = bis[w2]; }
            seq[n] = (float)bi;
        }
        __syncthreads();
    }
}

// ---------------- gather z (via LDS-staged w rows), write zq, accumulate loss ----------------
__global__ __launch_bounds__(256) void gather_kernel(
    const float* __restrict__ x, const float* __restrict__ w,
    const float* __restrict__ seqf, float* __restrict__ zq,
    double* __restrict__ loss_acc)
{
    __shared__ float ws[C_ * 64];      // [c][row] transposed, 64KB
    const int t   = threadIdx.x;
    const int nb  = blockIdx.x;
    const int b   = nb >> 6;
    const int hw0 = (nb & 63) << 6;
    {
        const int j = t >> 2, q = t & 3;
        const int idx = (int)seqf[b * HW_ + hw0 + j];
        const float* wrow = w + (size_t)idx * C_ + q * 64;
#pragma unroll
        for (int m = 0; m < 16; ++m) {
            const float4 v = *reinterpret_cast<const float4*>(wrow + m * 4);
            const int c = q * 64 + m * 4;
            ws[(c + 0) * 64 + j] = v.x;
            ws[(c + 1) * 64 + j] = v.y;
            ws[(c + 2) * 64 + j] = v.z;
            ws[(c + 3) * 64 + j] = v.w;
        }
    }
    __syncthreads();
    const int r  = t & 63;
    const int cg = t >> 6;
    const float* xb = x  + (size_t)b * CHW_ + hw0;
    float*       zb = zq + (size_t)b * CHW_ + hw0;
    float lsum = 0.f;
#pragma unroll 4
    for (int cc = 0; cc < 64; ++cc) {
        const int c = cg * 64 + cc;
        const float xv = xb[(size_t)c * HW_ + r];
        const float d  = ws[c * 64 + r] - xv;
        zb[(size_t)c * HW_ + r] = xv + d;
        lsum += d * d;
    }
#pragma unroll
    for (int off = 32; off >= 1; off >>= 1) lsum += __shfl_down(lsum, off, 64);
    __syncthreads();
    if ((t & 63) == 0) ws[t >> 6] = lsum;
    __syncthreads();
    if (t == 0)
        atomicAdd(loss_acc, (double)(ws[0] + ws[1] + ws[2] + ws[3]));
}

__global__ void finalize_kernel(const double* __restrict__ acc, float* __restrict__ loss_out)
{
    const double s = *acc;
    const float m = (float)(s / (double)((size_t)N_ * C_));
    loss_out[0] = m;
    loss_out[1] = m;
}

extern "C" void kernel_launch(void* const* d_in, const int* in_sizes, int n_in,
                              void* d_out, int out_size, void* d_ws, size_t ws_size,
                              hipStream_t stream)
{
    (void)in_sizes; (void)n_in; (void)out_size; (void)d_ws; (void)ws_size;
    const float* x = (const float*)d_in[0];
    const float* w = (const float*)d_in[1];
    float* out = (float*)d_out;

    float*         w_t    = out + WT_F;
    float*         wn     = out + WN_F;
    int*           wnu    = (int*)(out + WNU_F);
    unsigned char* wq     = (unsigned char*)(out + WQ_F);
    int*           rlist  = (int*)(out + RLIST_F);
    int*           rcount = (int*)(out + RCNT_F);
    unsigned*      wmaxb  = (unsigned*)(out + WMAX_F);
    float*         seq    = out + SEQ_OFF;
    double*        loss_acc = (double*)(out + LOSS_OFF);

    hipMemsetAsync((void*)wmaxb, 0, 4, stream);
    hipMemsetAsync((void*)rcount, 0, 4, stream);
    wmax_kernel<<<64, 256, 0, stream>>>(w, wmaxb);
    wprep_kernel<<<256, 256, 0, stream>>>(w, wmaxb, wq, w_t, wn, wnu);
    argmin_i8_kernel<<<512, 256, 0, stream>>>(x, wq, wnu, wmaxb, seq, rlist, rcount);
    rescue_kernel<<<1024, 256, 0, stream>>>(x, w_t, wn, rlist, rcount, seq);
    hipMemsetAsync((char*)d_out + (size_t)LOSS_OFF * 4, 0, 8, stream);
    gather_kernel<<<1024, 256, 0, stream>>>(x, w, seq, out, loss_acc);
    finalize_kernel<<<1, 1, 0, stream>>>(loss_acc, out + LOSS_OFF);
}